// Round 1
// baseline (1182.609 us; speedup 1.0000x reference)
//
#include <hip/hip_runtime.h>

#define NATOM 60000
#define NENV  600000
#define NEDGE 600000
#define GROW  512    // D * N_AXIS = 64 * 8
#define EROW  513

__device__ __forceinline__ float smoothf(float r) {
    const float RS_ = 3.0f, RC_ = 4.0f;
    float x = (r - RS_) / (RC_ - RS_);
    float mid = (1.0f / r) * (x * x * x * (-10.0f + x * (15.0f - 6.0f * x)) + 1.0f);
    return r < RS_ ? (1.0f / r) : (r < RC_ ? mid : 0.0f);
}

__device__ __forceinline__ float rdlane(float v, int l) {
    return __int_as_float(__builtin_amdgcn_readlane(__float_as_int(v), l));
}

// ---------------- CSR build ----------------

__global__ void k_zero(int* counts) {
    int i = blockIdx.x * 256 + threadIdx.x;
    if (i < NATOM) counts[i] = 0;
}

__global__ void k_count(const int* __restrict__ env_src, int* __restrict__ counts) {
    int e = blockIdx.x * 256 + threadIdx.x;
    if (e < NENV) atomicAdd(&counts[env_src[e]], 1);
}

__global__ __launch_bounds__(1024) void k_scan(const int* __restrict__ counts,
                                               int* __restrict__ offsets,
                                               int* __restrict__ cursor) {
    __shared__ int sums[1024];
    int tid = threadIdx.x;
    const int CH = (NATOM + 1023) / 1024;  // 59
    int b = tid * CH;
    int en = b + CH; if (en > NATOM) en = NATOM;
    int s = 0;
    for (int i = b; i < en; ++i) s += counts[i];
    sums[tid] = s;
    __syncthreads();
    for (int d = 1; d < 1024; d <<= 1) {
        int v = (tid >= d) ? sums[tid - d] : 0;
        __syncthreads();
        sums[tid] += v;
        __syncthreads();
    }
    int run = tid ? sums[tid - 1] : 0;
    for (int i = b; i < en; ++i) {
        offsets[i] = run;
        cursor[i] = run;
        run += counts[i];
    }
}

__global__ void k_fill(const int* __restrict__ env_src, int* __restrict__ cursor,
                       int* __restrict__ order) {
    int e = blockIdx.x * 256 + threadIdx.x;
    if (e < NENV) {
        int p = atomicAdd(&cursor[env_src[e]], 1);
        order[p] = e;
    }
}

// ---------------- per-atom: MLP + aggregate + bmm + normalize ----------------

__global__ __launch_bounds__(256) void k_atom(
    const float* __restrict__ env_vectors, const float* __restrict__ atom_attr,
    const int* __restrict__ env_nbr,
    const int* __restrict__ order, const int* __restrict__ offsets,
    const int* __restrict__ counts,
    const float* __restrict__ W1, const float* __restrict__ b1,
    const float* __restrict__ W2, const float* __restrict__ b2,
    const float* __restrict__ W3, const float* __restrict__ b3,
    float* __restrict__ g)
{
    int lane = threadIdx.x & 63;
    int n = blockIdx.x * 4 + (threadIdx.x >> 6);
    if (n >= NATOM) return;

    // thread `lane` owns output neuron `lane`; keep weight columns in VGPRs
    float w2c[64], w3c[64];
    #pragma unroll
    for (int i = 0; i < 64; ++i) {
        w2c[i] = W2[i * 64 + lane];
        w3c[i] = W3[i * 64 + lane];
    }
    float w1c[9];
    #pragma unroll
    for (int i = 0; i < 9; ++i) w1c[i] = W1[i * 64 + lane];
    float bb1 = b1[lane], bb2 = b2[lane], bb3 = b3[lane];

    int off = offsets[n], cnt = counts[n];
    float as0 = atom_attr[n * 4 + 0], as1 = atom_attr[n * 4 + 1],
          as2 = atom_attr[n * 4 + 2], as3 = atom_attr[n * 4 + 3];

    float a0 = 0.f, a1 = 0.f, a2 = 0.f, a3 = 0.f;  // aggr[lane][0..3] * cnt

    for (int k = 0; k < cnt; ++k) {
        int e = order[off + k];
        float vx = env_vectors[3 * e + 0];
        float vy = env_vectors[3 * e + 1];
        float vz = env_vectors[3 * e + 2];
        float r = sqrtf(vx * vx + vy * vy + vz * vz);
        if (r >= 4.0f) continue;  // snorm==0 -> msg==0 (count already includes it)
        int nb = env_nbr[e];
        float sn = smoothf(r);
        float inv_r = 1.0f / r;
        float d1 = sn * vx * inv_r, d2 = sn * vy * inv_r, d3 = sn * vz * inv_r;
        float an0 = atom_attr[nb * 4 + 0], an1 = atom_attr[nb * 4 + 1],
              an2 = atom_attr[nb * 4 + 2], an3 = atom_attr[nb * 4 + 3];

        // layer 1: x = [sn, attr_src(4), attr_nbr(4)]
        float acc = bb1;
        acc = fmaf(sn,  w1c[0], acc);
        acc = fmaf(as0, w1c[1], acc); acc = fmaf(as1, w1c[2], acc);
        acc = fmaf(as2, w1c[3], acc); acc = fmaf(as3, w1c[4], acc);
        acc = fmaf(an0, w1c[5], acc); acc = fmaf(an1, w1c[6], acc);
        acc = fmaf(an2, w1c[7], acc); acc = fmaf(an3, w1c[8], acc);
        float h = tanhf(acc);

        // layer 2: broadcast h across wave via readlane, 4-way partial sums
        float p0 = bb2, p1 = 0.f, p2 = 0.f, p3 = 0.f;
        #pragma unroll
        for (int i = 0; i < 64; i += 4) {
            p0 = fmaf(rdlane(h, i + 0), w2c[i + 0], p0);
            p1 = fmaf(rdlane(h, i + 1), w2c[i + 1], p1);
            p2 = fmaf(rdlane(h, i + 2), w2c[i + 2], p2);
            p3 = fmaf(rdlane(h, i + 3), w2c[i + 3], p3);
        }
        float h2 = tanhf((p0 + p1) + (p2 + p3));

        // layer 3
        p0 = bb3; p1 = 0.f; p2 = 0.f; p3 = 0.f;
        #pragma unroll
        for (int i = 0; i < 64; i += 4) {
            p0 = fmaf(rdlane(h2, i + 0), w3c[i + 0], p0);
            p1 = fmaf(rdlane(h2, i + 1), w3c[i + 1], p1);
            p2 = fmaf(rdlane(h2, i + 2), w3c[i + 2], p2);
            p3 = fmaf(rdlane(h2, i + 3), w3c[i + 3], p3);
        }
        float emb = (p0 + p1) + (p2 + p3);

        a0 = fmaf(emb, sn, a0);
        a1 = fmaf(emb, d1, a1);
        a2 = fmaf(emb, d2, a2);
        a3 = fmaf(emb, d3, a3);
    }

    float invc = 1.0f / fmaxf((float)cnt, 1.0f);
    a0 *= invc; a1 *= invc; a2 *= invc; a3 *= invc;

    // G[lane][e] = dot(aggr[lane], aggr[e]), e < 8
    float Gv[8];
    #pragma unroll
    for (int e2 = 0; e2 < 8; ++e2) {
        float r0 = rdlane(a0, e2), r1 = rdlane(a1, e2);
        float r2 = rdlane(a2, e2), r3 = rdlane(a3, e2);
        Gv[e2] = a0 * r0 + a1 * r1 + a2 * r2 + a3 * r3;
    }

    // mean over all 512
    float s = 0.f;
    #pragma unroll
    for (int e2 = 0; e2 < 8; ++e2) s += Gv[e2];
    #pragma unroll
    for (int m = 1; m < 64; m <<= 1) s += __shfl_xor(s, m, 64);
    float mean = s * (1.0f / 512.0f);

    float sq = 0.f;
    #pragma unroll
    for (int e2 = 0; e2 < 8; ++e2) { Gv[e2] -= mean; sq = fmaf(Gv[e2], Gv[e2], sq); }
    #pragma unroll
    for (int m = 1; m < 64; m <<= 1) sq += __shfl_xor(sq, m, 64);
    float rn = rsqrtf(sq);

    float4* o = (float4*)(g + (size_t)n * GROW + lane * 8);
    o[0] = make_float4(Gv[0] * rn, Gv[1] * rn, Gv[2] * rn, Gv[3] * rn);
    o[1] = make_float4(Gv[4] * rn, Gv[5] * rn, Gv[6] * rn, Gv[7] * rn);
}

// ---------------- per-edge: gather-add + inverse length ----------------

__global__ __launch_bounds__(256) void k_edge(
    const int* __restrict__ ei0, const int* __restrict__ ei1,
    const float* __restrict__ edge_length,
    const float* __restrict__ g, float* __restrict__ out_edge)
{
    int lane = threadIdx.x & 63;
    int e = blockIdx.x * 4 + (threadIdx.x >> 6);
    if (e >= NEDGE) return;
    int i0 = ei0[e], i1 = ei1[e];
    const float* g0 = g + (size_t)i0 * GROW;
    const float* g1 = g + (size_t)i1 * GROW;
    float* o = out_edge + (size_t)e * EROW;
    #pragma unroll
    for (int c = 0; c < 8; ++c) {
        int idx = lane + c * 64;  // fully coalesced: 256B per instruction
        o[idx] = g0[idx] + g1[idx];
    }
    if (lane == 0) o[512] = 1.0f / edge_length[e];
}

extern "C" void kernel_launch(void* const* d_in, const int* in_sizes, int n_in,
                              void* d_out, int out_size, void* d_ws, size_t ws_size,
                              hipStream_t stream) {
    const float* env_vectors = (const float*)d_in[0];
    const float* atom_attr   = (const float*)d_in[1];
    const int*   env_index   = (const int*)d_in[2];
    const int*   edge_index  = (const int*)d_in[3];
    const float* edge_length = (const float*)d_in[4];
    const float* W1 = (const float*)d_in[5];
    const float* b1 = (const float*)d_in[6];
    const float* W2 = (const float*)d_in[7];
    const float* b2 = (const float*)d_in[8];
    const float* W3 = (const float*)d_in[9];
    const float* b3 = (const float*)d_in[10];

    float* g        = (float*)d_out;
    float* out_edge = g + (size_t)NATOM * GROW;

    int* counts  = (int*)d_ws;
    int* offsets = counts + NATOM;
    int* cursor  = offsets + NATOM;
    int* order   = cursor + NATOM;

    const int* env_src = env_index;          // env_index[0]
    const int* env_nbr = env_index + NENV;   // env_index[1]
    const int* ei0 = edge_index;
    const int* ei1 = edge_index + NEDGE;

    hipLaunchKernelGGL(k_zero,  dim3((NATOM + 255) / 256), dim3(256), 0, stream, counts);
    hipLaunchKernelGGL(k_count, dim3((NENV + 255) / 256), dim3(256), 0, stream, env_src, counts);
    hipLaunchKernelGGL(k_scan,  dim3(1), dim3(1024), 0, stream, counts, offsets, cursor);
    hipLaunchKernelGGL(k_fill,  dim3((NENV + 255) / 256), dim3(256), 0, stream, env_src, cursor, order);
    hipLaunchKernelGGL(k_atom,  dim3(NATOM / 4), dim3(256), 0, stream,
                       env_vectors, atom_attr, env_nbr, order, offsets, counts,
                       W1, b1, W2, b2, W3, b3, g);
    hipLaunchKernelGGL(k_edge,  dim3(NEDGE / 4), dim3(256), 0, stream,
                       ei0, ei1, edge_length, g, out_edge);
}

// Round 2
// 1060.844 us; speedup vs baseline: 1.1148x; 1.1148x over previous
//
#include <hip/hip_runtime.h>

#define NATOM 60000
#define NENV  600000
#define NEDGE 600000
#define GROW  512    // D * N_AXIS = 64 * 8
#define EROW  513

__device__ __forceinline__ float smoothf(float r) {
    const float RS_ = 3.0f, RC_ = 4.0f;
    float x = (r - RS_) / (RC_ - RS_);
    float mid = (1.0f / r) * (x * x * x * (-10.0f + x * (15.0f - 6.0f * x)) + 1.0f);
    return r < RS_ ? (1.0f / r) : (r < RC_ ? mid : 0.0f);
}

// tanh(x) = 1 - 2/(exp(2x)+1); exp2-based, branchless, ~1e-6 abs err.
__device__ __forceinline__ float tanh_fast(float x) {
    float e = __builtin_amdgcn_exp2f(x * 2.8853900817779268f);  // exp(2x)
    return 1.0f - 2.0f * __builtin_amdgcn_rcpf(e + 1.0f);
}

__device__ __forceinline__ float rdlane(float v, int l) {
    return __int_as_float(__builtin_amdgcn_readlane(__float_as_int(v), l));
}

// ---------------- CSR build ----------------

__global__ void k_zero(int* counts) {
    int i = blockIdx.x * 256 + threadIdx.x;
    if (i < NATOM) counts[i] = 0;
}

__global__ void k_count(const int* __restrict__ env_src, int* __restrict__ counts) {
    int e = blockIdx.x * 256 + threadIdx.x;
    if (e < NENV) atomicAdd(&counts[env_src[e]], 1);
}

__global__ __launch_bounds__(1024) void k_scan(const int* __restrict__ counts,
                                               int* __restrict__ offsets,
                                               int* __restrict__ cursor) {
    __shared__ int sums[1024];
    int tid = threadIdx.x;
    const int CH = (NATOM + 1023) / 1024;  // 59
    int b = tid * CH;
    int en = b + CH; if (en > NATOM) en = NATOM;
    int s = 0;
    for (int i = b; i < en; ++i) s += counts[i];
    sums[tid] = s;
    __syncthreads();
    for (int d = 1; d < 1024; d <<= 1) {
        int v = (tid >= d) ? sums[tid - d] : 0;
        __syncthreads();
        sums[tid] += v;
        __syncthreads();
    }
    int run = tid ? sums[tid - 1] : 0;
    for (int i = b; i < en; ++i) {
        offsets[i] = run;
        cursor[i] = run;
        run += counts[i];
    }
}

__global__ void k_fill(const int* __restrict__ env_src, int* __restrict__ cursor,
                       int* __restrict__ order) {
    int e = blockIdx.x * 256 + threadIdx.x;
    if (e < NENV) {
        int p = atomicAdd(&cursor[env_src[e]], 1);
        order[p] = e;
    }
}

// ---------------- per-env MLP: thread = env, weights via SGPR ----------------

__global__ __launch_bounds__(256) void k_mlp(
    const float* __restrict__ env_vectors, const float* __restrict__ atom_attr,
    const int* __restrict__ env_src, const int* __restrict__ env_nbr,
    const float* __restrict__ W1, const float* __restrict__ b1,
    const float* __restrict__ W2, const float* __restrict__ b2,
    const float* __restrict__ W3, const float* __restrict__ b3,
    float* __restrict__ emb, float4* __restrict__ direct)
{
    int e = blockIdx.x * 256 + threadIdx.x;
    if (e >= NENV) return;

    float vx = env_vectors[3 * e + 0];
    float vy = env_vectors[3 * e + 1];
    float vz = env_vectors[3 * e + 2];
    float r = sqrtf(vx * vx + vy * vy + vz * vz);
    float sn = smoothf(r);
    float inv_r = 1.0f / r;
    direct[e] = make_float4(sn, sn * vx * inv_r, sn * vy * inv_r, sn * vz * inv_r);

    int sidx = env_src[e], nidx = env_nbr[e];
    float4 as = *(const float4*)(atom_attr + 4 * (size_t)sidx);
    float4 an = *(const float4*)(atom_attr + 4 * (size_t)nidx);

    // layer 1: 9 inputs -> 64, weights are thread-invariant -> s_load operands
    float h[64];
    #pragma unroll
    for (int j = 0; j < 64; ++j) {
        float a = b1[j];
        a = fmaf(sn,   W1[0 * 64 + j], a);
        a = fmaf(as.x, W1[1 * 64 + j], a);
        a = fmaf(as.y, W1[2 * 64 + j], a);
        a = fmaf(as.z, W1[3 * 64 + j], a);
        a = fmaf(as.w, W1[4 * 64 + j], a);
        a = fmaf(an.x, W1[5 * 64 + j], a);
        a = fmaf(an.y, W1[6 * 64 + j], a);
        a = fmaf(an.z, W1[7 * 64 + j], a);
        a = fmaf(an.w, W1[8 * 64 + j], a);
        h[j] = tanh_fast(a);
    }

    // layer 2: row-major weight walk (s_load_dwordx16-friendly), 64 indep accumulators
    float h2[64];
    #pragma unroll
    for (int j = 0; j < 64; ++j) h2[j] = b2[j];
    #pragma unroll
    for (int i = 0; i < 64; ++i) {
        float hi = h[i];
        #pragma unroll
        for (int j = 0; j < 64; ++j) h2[j] = fmaf(hi, W2[i * 64 + j], h2[j]);
    }
    #pragma unroll
    for (int j = 0; j < 64; ++j) h2[j] = tanh_fast(h2[j]);

    // layer 3
    float o[64];
    #pragma unroll
    for (int j = 0; j < 64; ++j) o[j] = b3[j];
    #pragma unroll
    for (int i = 0; i < 64; ++i) {
        float hi = h2[i];
        #pragma unroll
        for (int j = 0; j < 64; ++j) o[j] = fmaf(hi, W3[i * 64 + j], o[j]);
    }

    float* orow = emb + (size_t)e * 64;
    #pragma unroll
    for (int j = 0; j < 64; ++j) orow[j] = o[j];
}

// ---------------- per-atom: aggregate + bmm + normalize ----------------

__global__ __launch_bounds__(256) void k_aggr(
    const float* __restrict__ emb, const float4* __restrict__ direct,
    const int* __restrict__ order, const int* __restrict__ offsets,
    const int* __restrict__ counts, float* __restrict__ g)
{
    int lane = threadIdx.x & 63;
    int n = blockIdx.x * 4 + (threadIdx.x >> 6);
    if (n >= NATOM) return;

    int off = offsets[n], cnt = counts[n];
    float a0 = 0.f, a1 = 0.f, a2 = 0.f, a3 = 0.f;

    for (int k = 0; k < cnt; ++k) {
        int e = order[off + k];
        float4 d4 = direct[e];                       // wave-uniform 16B broadcast
        float em = emb[(size_t)e * 64 + lane];       // coalesced 256B row
        a0 = fmaf(em, d4.x, a0);
        a1 = fmaf(em, d4.y, a1);
        a2 = fmaf(em, d4.z, a2);
        a3 = fmaf(em, d4.w, a3);
    }

    float invc = 1.0f / fmaxf((float)cnt, 1.0f);
    a0 *= invc; a1 *= invc; a2 *= invc; a3 *= invc;

    // G[lane][e2] = dot(aggr[lane], aggr[e2]), e2 < 8
    float Gv[8];
    #pragma unroll
    for (int e2 = 0; e2 < 8; ++e2) {
        float r0 = rdlane(a0, e2), r1 = rdlane(a1, e2);
        float r2 = rdlane(a2, e2), r3 = rdlane(a3, e2);
        Gv[e2] = a0 * r0 + a1 * r1 + a2 * r2 + a3 * r3;
    }

    float s = 0.f;
    #pragma unroll
    for (int e2 = 0; e2 < 8; ++e2) s += Gv[e2];
    #pragma unroll
    for (int m = 1; m < 64; m <<= 1) s += __shfl_xor(s, m, 64);
    float mean = s * (1.0f / 512.0f);

    float sq = 0.f;
    #pragma unroll
    for (int e2 = 0; e2 < 8; ++e2) { Gv[e2] -= mean; sq = fmaf(Gv[e2], Gv[e2], sq); }
    #pragma unroll
    for (int m = 1; m < 64; m <<= 1) sq += __shfl_xor(sq, m, 64);
    float rn = rsqrtf(sq);

    float4* og = (float4*)(g + (size_t)n * GROW + lane * 8);
    og[0] = make_float4(Gv[0] * rn, Gv[1] * rn, Gv[2] * rn, Gv[3] * rn);
    og[1] = make_float4(Gv[4] * rn, Gv[5] * rn, Gv[6] * rn, Gv[7] * rn);
}

// ---------------- per-edge: gather-add, nontemporal stores ----------------

__global__ __launch_bounds__(256) void k_edge(
    const int* __restrict__ ei0, const int* __restrict__ ei1,
    const float* __restrict__ edge_length,
    const float* __restrict__ g, float* __restrict__ out_edge)
{
    int lane = threadIdx.x & 63;
    int e = blockIdx.x * 4 + (threadIdx.x >> 6);
    if (e >= NEDGE) return;
    int i0 = ei0[e], i1 = ei1[e];
    const float* g0 = g + (size_t)i0 * GROW;
    const float* g1 = g + (size_t)i1 * GROW;
    float* o = out_edge + (size_t)e * EROW;
    #pragma unroll
    for (int c = 0; c < 8; ++c) {
        int idx = lane + c * 64;  // 256B contiguous per instruction
        __builtin_nontemporal_store(g0[idx] + g1[idx], &o[idx]);
    }
    if (lane == 0) __builtin_nontemporal_store(1.0f / edge_length[e], &o[512]);
}

extern "C" void kernel_launch(void* const* d_in, const int* in_sizes, int n_in,
                              void* d_out, int out_size, void* d_ws, size_t ws_size,
                              hipStream_t stream) {
    const float* env_vectors = (const float*)d_in[0];
    const float* atom_attr   = (const float*)d_in[1];
    const int*   env_index   = (const int*)d_in[2];
    const int*   edge_index  = (const int*)d_in[3];
    const float* edge_length = (const float*)d_in[4];
    const float* W1 = (const float*)d_in[5];
    const float* b1 = (const float*)d_in[6];
    const float* W2 = (const float*)d_in[7];
    const float* b2 = (const float*)d_in[8];
    const float* W3 = (const float*)d_in[9];
    const float* b3 = (const float*)d_in[10];

    float* g        = (float*)d_out;
    float* out_edge = g + (size_t)NATOM * GROW;

    int* counts  = (int*)d_ws;
    int* offsets = counts + NATOM;
    int* cursor  = offsets + NATOM;
    int* order   = cursor + NATOM;                 // NENV ints
    float*  embw   = (float*)(order + NENV);       // 600000*64 floats (153.6 MB), 16B-aligned
    float4* direct = (float4*)(embw + (size_t)NENV * 64);  // 600000 float4 (9.6 MB)

    const int* env_src = env_index;          // env_index[0]
    const int* env_nbr = env_index + NENV;   // env_index[1]
    const int* ei0 = edge_index;
    const int* ei1 = edge_index + NEDGE;

    hipLaunchKernelGGL(k_zero,  dim3((NATOM + 255) / 256), dim3(256), 0, stream, counts);
    hipLaunchKernelGGL(k_count, dim3((NENV + 255) / 256), dim3(256), 0, stream, env_src, counts);
    hipLaunchKernelGGL(k_scan,  dim3(1), dim3(1024), 0, stream, counts, offsets, cursor);
    hipLaunchKernelGGL(k_fill,  dim3((NENV + 255) / 256), dim3(256), 0, stream, env_src, cursor, order);
    hipLaunchKernelGGL(k_mlp,   dim3((NENV + 255) / 256), dim3(256), 0, stream,
                       env_vectors, atom_attr, env_src, env_nbr,
                       W1, b1, W2, b2, W3, b3, embw, direct);
    hipLaunchKernelGGL(k_aggr,  dim3(NATOM / 4), dim3(256), 0, stream,
                       embw, direct, order, offsets, counts, g);
    hipLaunchKernelGGL(k_edge,  dim3(NEDGE / 4), dim3(256), 0, stream,
                       ei0, ei1, edge_length, g, out_edge);
}